// Round 1
// baseline (76.662 us; speedup 1.0000x reference)
//
#include <hip/hip_runtime.h>
#include <math.h>

// Problem constants (from reference)
#define NUM_T   8      // NUM_NODE_TYPES
#define TIN     16     // 2 * NUM_NODE_TYPES
#define HID     64     // HIDDEN
#define OUTD    16     // D*D
#define LN_EPS  1e-5f

// ---------------------------------------------------------------------------
// Kernel A: build the 64-entry (type_src, type_tgt) -> 16-float output table.
// One block, 64 threads; thread t handles pair (ts = t>>3, tt = t&7).
// ---------------------------------------------------------------------------
__global__ void build_table_kernel(const float* __restrict__ ln_g,
                                   const float* __restrict__ ln_b,
                                   const float* __restrict__ W1,   // [16][64]
                                   const float* __restrict__ b1,   // [64]
                                   const float* __restrict__ W2,   // [64][16]
                                   const float* __restrict__ b2,   // [16]
                                   float* __restrict__ table)      // [64][16]
{
    int t = threadIdx.x;
    if (t >= 64) return;
    int ts = t >> 3;
    int tt = t & 7;

    // h = concat(onehot(ts), onehot(tt)) : exactly two ones.
    // LayerNorm (computed generically for safety).
    float mu = 2.0f / 16.0f;
    float var = 0.0f;
    #pragma unroll
    for (int j = 0; j < TIN; ++j) {
        float h = (j == ts || j == (8 + tt)) ? 1.0f : 0.0f;
        float d = h - mu;
        var += d * d;
    }
    var *= (1.0f / 16.0f);
    float inv = rsqrtf(var + LN_EPS);

    float hn[TIN];
    #pragma unroll
    for (int j = 0; j < TIN; ++j) {
        float h = (j == ts || j == (8 + tt)) ? 1.0f : 0.0f;
        hn[j] = (h - mu) * inv * ln_g[j] + ln_b[j];
    }

    // MLP: s = relu(hn @ W1 + b1) @ W2 + b2
    float s[OUTD];
    #pragma unroll
    for (int o = 0; o < OUTD; ++o) s[o] = b2[o];

    for (int k = 0; k < HID; ++k) {
        float a = b1[k];
        #pragma unroll
        for (int j = 0; j < TIN; ++j) a += hn[j] * W1[j * HID + k];
        a = fmaxf(a, 0.0f);
        #pragma unroll
        for (int o = 0; o < OUTD; ++o) s[o] += a * W2[k * OUTD + o];
    }

    // Per-row (4-wide) softmax, then I - P.
    float outv[OUTD];
    #pragma unroll
    for (int r = 0; r < 4; ++r) {
        float s0 = s[4*r+0], s1 = s[4*r+1], s2 = s[4*r+2], s3 = s[4*r+3];
        float m = fmaxf(fmaxf(s0, s1), fmaxf(s2, s3));
        float e0 = expf(s0 - m), e1 = expf(s1 - m),
              e2 = expf(s2 - m), e3 = expf(s3 - m);
        float rs = 1.0f / (e0 + e1 + e2 + e3);
        outv[4*r+0] = (r == 0 ? 1.0f : 0.0f) - e0 * rs;
        outv[4*r+1] = (r == 1 ? 1.0f : 0.0f) - e1 * rs;
        outv[4*r+2] = (r == 2 ? 1.0f : 0.0f) - e2 * rs;
        outv[4*r+3] = (r == 3 ? 1.0f : 0.0f) - e3 * rs;
    }

    float* dst = table + t * OUTD;
    #pragma unroll
    for (int o = 0; o < OUTD; ++o) dst[o] = outv[o];
}

// ---------------------------------------------------------------------------
// Kernel B: per-edge gather of the table row, coalesced float4 stores.
// 4 lanes per edge; lane's quad index q picks one float4 of the 16-float row.
// 256 threads/block -> 64 edges per block-iteration; grid-stride loop.
// ---------------------------------------------------------------------------
__global__ __launch_bounds__(256) void
scatter_edges_kernel(const int* __restrict__ row,
                     const int* __restrict__ col,
                     const int* __restrict__ ntypes,
                     const float4* __restrict__ table4,  // [64][4]
                     float4* __restrict__ out4,          // [E][4]
                     int E)
{
    __shared__ float4 lds_table[256];            // 64 pairs * 4 quads = 4 KB
    lds_table[threadIdx.x] = table4[threadIdx.x];
    __syncthreads();

    const int q      = threadIdx.x & 3;
    const int lane_e = threadIdx.x >> 2;         // 0..63
    const int stride = gridDim.x * 64;

    for (int e = blockIdx.x * 64 + lane_e; e < E; e += stride) {
        int r = row[e];
        int c = col[e];
        int pair = ntypes[r] * NUM_T + ntypes[c];
        out4[e * 4 + q] = lds_table[pair * 4 + q];
    }
}

// ---------------------------------------------------------------------------
extern "C" void kernel_launch(void* const* d_in, const int* in_sizes, int n_in,
                              void* d_out, int out_size, void* d_ws, size_t ws_size,
                              hipStream_t stream)
{
    // Inputs (setup_inputs order): x, edge_index, node_types, ln_g, ln_b, W1, b1, W2, b2
    const int*   edge_index = (const int*)d_in[1];   // [2][E] int32
    const int*   ntypes     = (const int*)d_in[2];   // [N] int32
    const float* ln_g       = (const float*)d_in[3];
    const float* ln_b       = (const float*)d_in[4];
    const float* W1         = (const float*)d_in[5];
    const float* b1         = (const float*)d_in[6];
    const float* W2         = (const float*)d_in[7];
    const float* b2         = (const float*)d_in[8];

    const int E = in_sizes[1] / 2;

    float* table = (float*)d_ws;   // 64*16*4 = 4 KB scratch

    build_table_kernel<<<1, 64, 0, stream>>>(ln_g, ln_b, W1, b1, W2, b2, table);

    const int blocks = 2048;       // 256 CU * 8; grid-stride covers E
    scatter_edges_kernel<<<blocks, 256, 0, stream>>>(
        edge_index, edge_index + E, ntypes,
        (const float4*)table, (float4*)d_out, E);
}

// Round 3
// 54.089 us; speedup vs baseline: 1.4173x; 1.4173x over previous
//
#include <hip/hip_runtime.h>
#include <math.h>

// Problem constants (from reference)
#define NUM_T   8      // NUM_NODE_TYPES
#define TIN     16     // 2 * NUM_NODE_TYPES
#define HID     64     // HIDDEN
#define OUTD    16     // D*D
#define LN_EPS  1e-5f

// Native clang vector type: __builtin_nontemporal_store accepts this
// (HIP's float4 is a class and is rejected).
typedef float f32x4 __attribute__((ext_vector_type(4)));

// ---------------------------------------------------------------------------
// Kernel A: build the 64-entry (type_src, type_tgt) -> 16-float output table.
// 256 threads: thread t = pair p (t>>2) x k-group kg (t&3).
// Weights staged in LDS via coalesced loads first (the v1 kernel was a single
// wave doing ~2k serialized scalar loads -> tens of microseconds).
// ---------------------------------------------------------------------------
__global__ __launch_bounds__(256) void
build_table_kernel(const float* __restrict__ ln_g,
                   const float* __restrict__ ln_b,
                   const float* __restrict__ W1,   // [16][64]
                   const float* __restrict__ b1,   // [64]
                   const float* __restrict__ W2,   // [64][16]
                   const float* __restrict__ b2,   // [16]
                   f32x4* __restrict__ table4)     // [64][4] float4
{
    __shared__ float sW1[TIN * HID];   // 4 KB
    __shared__ float sW2[HID * OUTD];  // 4 KB
    __shared__ float sb1[HID];
    __shared__ float sg[TIN], sb[TIN], sb2[OUTD];

    const int t = threadIdx.x;

    // Coalesced staging of all weights.
    for (int i = t; i < TIN * HID; i += 256) sW1[i] = W1[i];
    for (int i = t; i < HID * OUTD; i += 256) sW2[i] = W2[i];
    if (t < HID) sb1[t] = b1[t];
    if (t < TIN) { sg[t] = ln_g[t]; sb[t] = ln_b[t]; }
    if (t < OUTD) sb2[t] = b2[t];
    __syncthreads();

    const int p  = t >> 2;       // pair 0..63
    const int kg = t & 3;        // k-group 0..3 (16 k's each)
    const int ts = p >> 3;
    const int tt = p & 7;

    // LayerNorm of the two-hot vector (computed generically).
    const float mu = 2.0f / 16.0f;
    float var = 0.0f;
    #pragma unroll
    for (int j = 0; j < TIN; ++j) {
        float h = (j == ts || j == (8 + tt)) ? 1.0f : 0.0f;
        float d = h - mu;
        var += d * d;
    }
    var *= (1.0f / 16.0f);
    const float inv = rsqrtf(var + LN_EPS);

    float hn[TIN];
    #pragma unroll
    for (int j = 0; j < TIN; ++j) {
        float h = (j == ts || j == (8 + tt)) ? 1.0f : 0.0f;
        hn[j] = (h - mu) * inv * sg[j] + sb[j];
    }

    // Partial MLP over this thread's 16 k's.
    float s[OUTD];
    #pragma unroll
    for (int o = 0; o < OUTD; ++o) s[o] = 0.0f;

    const int k0 = kg * 16;
    for (int k = k0; k < k0 + 16; ++k) {
        float a = sb1[k];
        #pragma unroll
        for (int j = 0; j < TIN; ++j) a += hn[j] * sW1[j * HID + k];
        a = fmaxf(a, 0.0f);
        #pragma unroll
        for (int o = 0; o < OUTD; ++o) s[o] += a * sW2[k * OUTD + o];
    }

    // Reduce the 4 k-group partials across the aligned 4-lane group.
    #pragma unroll
    for (int o = 0; o < OUTD; ++o) {
        s[o] += __shfl_xor(s[o], 1);
        s[o] += __shfl_xor(s[o], 2);
        s[o] += sb2[o];
    }

    // Each of the 4 lanes finishes one softmax row (r = kg) and stores float4.
    const int r = kg;
    float s0 = s[4*r+0], s1 = s[4*r+1], s2 = s[4*r+2], s3 = s[4*r+3];
    float m  = fmaxf(fmaxf(s0, s1), fmaxf(s2, s3));
    float e0 = expf(s0 - m), e1 = expf(s1 - m),
          e2 = expf(s2 - m), e3 = expf(s3 - m);
    float rs = 1.0f / (e0 + e1 + e2 + e3);
    f32x4 outv;
    outv.x = (r == 0 ? 1.0f : 0.0f) - e0 * rs;
    outv.y = (r == 1 ? 1.0f : 0.0f) - e1 * rs;
    outv.z = (r == 2 ? 1.0f : 0.0f) - e2 * rs;
    outv.w = (r == 3 ? 1.0f : 0.0f) - e3 * rs;

    table4[t] = outv;   // t == p*4 + r : coalesced
}

// ---------------------------------------------------------------------------
// Kernel B: per-edge gather of the table row, coalesced float4 stores.
// 4 lanes per edge. LDS table padded to stride 5 (bank-conflict fix:
// stride 4 float4 made the bank depend only on pair&1 -> ~8-way conflicts).
// ---------------------------------------------------------------------------
__global__ __launch_bounds__(256) void
scatter_edges_kernel(const int* __restrict__ row,
                     const int* __restrict__ col,
                     const int* __restrict__ ntypes,
                     const f32x4* __restrict__ table4,  // [64][4]
                     f32x4* __restrict__ out4,          // [E][4]
                     int E)
{
    __shared__ f32x4 lds_table[64 * 5];          // padded: row stride 5
    {
        int p = threadIdx.x >> 2, q = threadIdx.x & 3;
        lds_table[p * 5 + q] = table4[threadIdx.x];
    }
    __syncthreads();

    const int q      = threadIdx.x & 3;
    const int lane_e = threadIdx.x >> 2;         // 0..63
    const int stride = gridDim.x * 64;

    for (int e = blockIdx.x * 64 + lane_e; e < E; e += stride) {
        int r = row[e];
        int c = col[e];
        int pair = ntypes[r] * NUM_T + ntypes[c];
        f32x4 v = lds_table[pair * 5 + q];
        __builtin_nontemporal_store(v, &out4[e * 4 + q]);
    }
}

// ---------------------------------------------------------------------------
extern "C" void kernel_launch(void* const* d_in, const int* in_sizes, int n_in,
                              void* d_out, int out_size, void* d_ws, size_t ws_size,
                              hipStream_t stream)
{
    // Inputs (setup_inputs order): x, edge_index, node_types, ln_g, ln_b, W1, b1, W2, b2
    const int*   edge_index = (const int*)d_in[1];   // [2][E] int32
    const int*   ntypes     = (const int*)d_in[2];   // [N] int32
    const float* ln_g       = (const float*)d_in[3];
    const float* ln_b       = (const float*)d_in[4];
    const float* W1         = (const float*)d_in[5];
    const float* b1         = (const float*)d_in[6];
    const float* W2         = (const float*)d_in[7];
    const float* b2         = (const float*)d_in[8];

    const int E = in_sizes[1] / 2;

    f32x4* table4 = (f32x4*)d_ws;   // 64*16*4 = 4 KB scratch

    build_table_kernel<<<1, 256, 0, stream>>>(ln_g, ln_b, W1, b1, W2, b2, table4);

    const int blocks = 2048;        // 256 CU * 8; grid-stride covers E
    scatter_edges_kernel<<<blocks, 256, 0, stream>>>(
        edge_index, edge_index + E, ntypes,
        table4, (f32x4*)d_out, E);
}